// Round 6
// baseline (421.638 us; speedup 1.0000x reference)
//
#include <hip/hip_runtime.h>
#include <math.h>

#define NN 8192
#define KDIM 512
#define DD 256
#define CS 32    // prefix chunk size
#define NC 256   // number of chunks
#define NB 256   // grid blocks (cooperative, 1/CU)

typedef float4 f4;
typedef __attribute__((ext_vector_type(4))) float f4v;  // native vec for nontemporal

__device__ __forceinline__ float dot4(const f4& x, const f4& y) {
  return x.x * y.x + x.y * y.y + x.z * y.z + x.w * y.w;
}

// Lightweight grid barrier: arrival counter + generation flag, agent scope.
// Co-residency guaranteed by cooperative launch. threadfence = L2 wb/inv on
// gfx950 (cross-XCD visibility). s_sleep(1) spin (64 cy) -- no long backoff.
__device__ __forceinline__ void gridbar(unsigned* cnt, unsigned* gen) {
  __syncthreads();
  if (threadIdx.x == 0) {
    __threadfence();  // make this block's writes globally visible
    unsigned g = __hip_atomic_load(gen, __ATOMIC_RELAXED, __HIP_MEMORY_SCOPE_AGENT);
    unsigned a = __hip_atomic_fetch_add(cnt, 1u, __ATOMIC_ACQ_REL, __HIP_MEMORY_SCOPE_AGENT);
    if (a == NB - 1) {
      __hip_atomic_store(cnt, 0u, __ATOMIC_RELAXED, __HIP_MEMORY_SCOPE_AGENT);
      __hip_atomic_store(gen, g + 1u, __ATOMIC_RELEASE, __HIP_MEMORY_SCOPE_AGENT);
    } else {
      while (__hip_atomic_load(gen, __ATOMIC_ACQUIRE, __HIP_MEMORY_SCOPE_AGENT) == g)
        __builtin_amdgcn_s_sleep(1);
    }
    __threadfence();  // invalidate stale caches before reading others' data
  }
  __syncthreads();
}

// ONE cooperative kernel: gemm(+s,t) | E/c/rank | chunk | prefix | finalize | astream
__global__ __launch_bounds__(256) void k_fused(const float* __restrict__ X,
                                               const float* __restrict__ W,
                                               const float* __restrict__ av,
                                               float* __restrict__ out,
                                               float* __restrict__ Ab,
                                               float* __restrict__ wsp) {
  // ws vector map
  float* s  = wsp + 0 * NN;
  float* t  = wsp + 1 * NN;
  float* E1 = wsp + 2 * NN;
  float* E2 = wsp + 3 * NN;
  float* c1 = wsp + 4 * NN;
  float* c2 = wsp + 5 * NN;
  float* f1 = wsp + 6 * NN;
  float* f2 = wsp + 7 * NN;
  // A-region scratch map (overwritten by phase F / re-zeroed barrier by memset)
  float* H     = out;
  float* PRE1  = Ab;                    // 8193*256 (padded to 4194304)
  float* PRE2  = Ab + 4194304;
  float* Ctot1 = Ab + 8388608;          // NC*DD
  float* Ctot2 = Ctot1 + NC * DD;
  float* cs1   = Ctot2 + NC * DD;       // NC
  float* cs2   = cs1 + NC;
  float* p1s   = cs2 + NC;              // NN+1
  float* p2s   = p1s + (NN + 256);
  float* tsort = p2s + (NN + 256);      // NN
  int*   perm  = (int*)(tsort + NN);    // NN
  unsigned* bcnt = (unsigned*)(Ab + 8600000);  // zeroed by memsetAsync
  unsigned* bgen = bcnt + 1;

  __shared__ float smem[8192];   // union: gemm tiles (6144) / ts[8192]
  __shared__ float sa[NC], sb[NC];
  __shared__ int   pms[CS];
  __shared__ float pe1[CS], pe2[CS];
  __shared__ float lred[4];
  __shared__ float srow[32], f1r[32], f2r[32];

  const int b = blockIdx.x;
  const int tid = threadIdx.x;
  const int wid = tid >> 6, lane = tid & 63;

  // ================= phase A: GEMM (2 col-tiles) + s,t tail =================
  {
    float (*Xs)[64]  = (float(*)[64])smem;          // [32][64]
    float (*Ws)[128] = (float(*)[128])(smem + 2048);// [32][128]
    const int tx = tid & 15;
    const int ty = tid >> 4;
    const int rt = b >> 1;
    const int cp = b & 1;
    const int r0 = rt * 64;
    const int c0 = cp * 128;
    float acc0[4][4] = {};
    float acc1[4][4] = {};
    for (int k0 = 0; k0 < KDIM; k0 += 32) {
#pragma unroll
      for (int q = 0; q < 2; ++q) {
        int fi = tid + q * 256;      // X tile: 64 rows x 8 f4
        int r = fi >> 3;
        int kq = fi & 7;
        f4 v = *reinterpret_cast<const f4*>(&X[(size_t)(r0 + r) * KDIM + k0 + kq * 4]);
        Xs[kq * 4 + 0][r] = v.x; Xs[kq * 4 + 1][r] = v.y;
        Xs[kq * 4 + 2][r] = v.z; Xs[kq * 4 + 3][r] = v.w;
      }
#pragma unroll
      for (int q = 0; q < 4; ++q) {
        int fi = tid + q * 256;      // W tile: 32 k x 32 f4 (128 cols)
        int k = fi >> 5;
        int cw = fi & 31;
        f4 v = *reinterpret_cast<const f4*>(&W[(size_t)(k0 + k) * DD + c0 + cw * 4]);
        *reinterpret_cast<f4*>(&Ws[k][cw * 4]) = v;
      }
      __syncthreads();
#pragma unroll
      for (int k = 0; k < 32; ++k) {
        f4 xv = *reinterpret_cast<const f4*>(&Xs[k][ty * 4]);
        f4 wa = *reinterpret_cast<const f4*>(&Ws[k][tx * 4]);
        f4 wb = *reinterpret_cast<const f4*>(&Ws[k][64 + tx * 4]);
        float xs[4] = {xv.x, xv.y, xv.z, xv.w};
        float wsa[4] = {wa.x, wa.y, wa.z, wa.w};
        float wsb[4] = {wb.x, wb.y, wb.z, wb.w};
#pragma unroll
        for (int i = 0; i < 4; ++i)
#pragma unroll
          for (int j = 0; j < 4; ++j) {
            acc0[i][j] += xs[i] * wsa[j];
            acc1[i][j] += xs[i] * wsb[j];
          }
      }
      __syncthreads();
    }
#pragma unroll
    for (int i = 0; i < 4; ++i) {
      f4 v0 = {acc0[i][0], acc0[i][1], acc0[i][2], acc0[i][3]};
      f4 v1 = {acc1[i][0], acc1[i][1], acc1[i][2], acc1[i][3]};
      *reinterpret_cast<f4*>(&H[(size_t)(r0 + ty * 4 + i) * DD + c0 + tx * 4]) = v0;
      *reinterpret_cast<f4*>(&H[(size_t)(r0 + ty * 4 + i) * DD + c0 + 64 + tx * 4]) = v1;
    }

    if (cp == 0) {
      // s,t for rows r0..r0+63 via identity s = X@(W@a1), t = X@(W@a2)
      float* wv1 = smem;        // [512]
      float* wv2 = smem + 512;  // [512]
      for (int k = tid; k < KDIM; k += 256) {
        float a1acc = 0.f, a2acc = 0.f;
#pragma unroll 8
        for (int d4 = 0; d4 < DD / 4; ++d4) {
          f4 wrow = *reinterpret_cast<const f4*>(&W[(size_t)k * DD + d4 * 4]);
          f4 a1v = *reinterpret_cast<const f4*>(&av[d4 * 4]);
          f4 a2v = *reinterpret_cast<const f4*>(&av[DD + d4 * 4]);
          a1acc += dot4(wrow, a1v);
          a2acc += dot4(wrow, a2v);
        }
        wv1[k] = a1acc;
        wv2[k] = a2acc;
      }
      __syncthreads();
      f4 w1a = *reinterpret_cast<const f4*>(&wv1[lane * 8]);
      f4 w1b = *reinterpret_cast<const f4*>(&wv1[lane * 8 + 4]);
      f4 w2a = *reinterpret_cast<const f4*>(&wv2[lane * 8]);
      f4 w2b = *reinterpret_cast<const f4*>(&wv2[lane * 8 + 4]);
      for (int rr = 0; rr < 16; ++rr) {
        int i = r0 + wid * 16 + rr;
        f4 xa = *reinterpret_cast<const f4*>(&X[(size_t)i * KDIM + lane * 8]);
        f4 xb = *reinterpret_cast<const f4*>(&X[(size_t)i * KDIM + lane * 8 + 4]);
        float p1 = dot4(xa, w1a) + dot4(xb, w1b);
        float p2 = dot4(xa, w2a) + dot4(xb, w2b);
        for (int off = 32; off > 0; off >>= 1) {
          p1 += __shfl_down(p1, off);
          p2 += __shfl_down(p2, off);
        }
        if (lane == 0) { s[i] = p1; t[i] = p2; }
      }
    }
  }
  gridbar(bcnt, bgen);  // H, s, t complete

  // ================= phase B: tmax, E1/E2, c1/c2, rank+scatter =================
  {
    float* ts = smem;
    float m = -1e30f;
#pragma unroll
    for (int q = 0; q < NN / 1024; ++q) {
      int idx = (q * 256 + tid) * 4;
      f4 v = *reinterpret_cast<const f4*>(&t[idx]);
      *reinterpret_cast<f4*>(&ts[idx]) = v;
      m = fmaxf(m, fmaxf(fmaxf(v.x, v.y), fmaxf(v.z, v.w)));
    }
    for (int off = 32; off > 0; off >>= 1) m = fmaxf(m, __shfl_down(m, off));
    if (lane == 0) lred[wid] = m;
    __syncthreads();
    float tmax = fmaxf(fmaxf(lred[0], lred[1]), fmaxf(lred[2], lred[3]));

    if (tid < 32) {
      int i = b * 32 + tid;
      float ti = ts[i];
      E1[i] = expf(ti);
      E2[i] = expf(0.2f * ti);
      float si = s[i];
      float e = si + tmax;
      float mm = e > 0.f ? e : 0.2f * e;
      c1[i] = expf(si - mm);
      c2[i] = expf(0.2f * si - mm);
    }

    float tkv[8]; int jj[8]; int cnt[8];
#pragma unroll
    for (int q = 0; q < 8; ++q) {
      jj[q] = b * 32 + wid * 8 + q;
      tkv[q] = ts[jj[q]];
      cnt[q] = 0;
    }
    for (int m2 = 0; m2 < NN / 64; ++m2) {
      int i = lane + m2 * 64;
      float v = ts[i];
#pragma unroll
      for (int q = 0; q < 8; ++q)
        cnt[q] += (v < tkv[q]) || (v == tkv[q] && i < jj[q]);
    }
#pragma unroll
    for (int q = 0; q < 8; ++q) {
      int c = cnt[q];
      for (int off = 32; off > 0; off >>= 1) c += __shfl_down(c, off);
      if (lane == 0) { tsort[c] = tkv[q]; perm[c] = jj[q]; }
    }
  }
  gridbar(bcnt, bgen);  // E1, E2, c1, c2, tsort, perm complete

  // ================= phase C: chunk totals (chunk b) =================
  {
    int d = tid;
    if (d < CS) {
      int p = perm[b * CS + d];
      pms[d] = p;
      pe1[d] = E1[p];
      pe2[d] = E2[p];
    }
    __syncthreads();
    float s1 = 0.f, s2 = 0.f, a1 = 0.f, a2 = 0.f;
#pragma unroll 4
    for (int kk = 0; kk < CS; ++kk) {
      float e1 = pe1[kk], e2 = pe2[kk];
      float h = H[(size_t)pms[kk] * DD + d];
      s1 += e1 * h; s2 += e2 * h;
      a1 += e1;     a2 += e2;
    }
    Ctot1[b * DD + d] = s1;
    Ctot2[b * DD + d] = s2;
    if (d == 0) { cs1[b] = a1; cs2[b] = a2; }
  }
  gridbar(bcnt, bgen);  // Ctot, cs complete

  // ================= phase D: exclusive prefix (chunk b) =================
  {
    int d = tid;
    // chunk offset: sum Ctot[0..b-1][d], pipelined (split accumulators)
    float r1a = 0.f, r1b = 0.f, r2a = 0.f, r2b = 0.f;
    int cc = 0;
    for (; cc + 4 <= b; cc += 4) {
      r1a += Ctot1[(cc + 0) * DD + d];
      r1b += Ctot1[(cc + 1) * DD + d];
      r1a += Ctot1[(cc + 2) * DD + d];
      r1b += Ctot1[(cc + 3) * DD + d];
      r2a += Ctot2[(cc + 0) * DD + d];
      r2b += Ctot2[(cc + 1) * DD + d];
      r2a += Ctot2[(cc + 2) * DD + d];
      r2b += Ctot2[(cc + 3) * DD + d];
    }
    for (; cc < b; ++cc) {
      r1a += Ctot1[cc * DD + d];
      r2a += Ctot2[cc * DD + d];
    }
    float r1 = r1a + r1b, r2 = r2a + r2b;
    if (d < CS) {
      int p = perm[b * CS + d];
      pms[d] = p;
      pe1[d] = E1[p];
      pe2[d] = E2[p];
    }
    sa[d] = (d < b) ? cs1[d] : 0.f;
    sb[d] = (d < b) ? cs2[d] : 0.f;
    __syncthreads();
    for (int off = 128; off > 0; off >>= 1) {
      if (d < off) { sa[d] += sa[d + off]; sb[d] += sb[d + off]; }
      __syncthreads();
    }
    float sr1 = sa[0], sr2 = sb[0];
#pragma unroll 2
    for (int kk = 0; kk < CS; ++kk) {
      int k = b * CS + kk;
      PRE1[(size_t)k * DD + d] = r1;
      PRE2[(size_t)k * DD + d] = r2;
      float e1 = pe1[kk], e2 = pe2[kk];
      float h = H[(size_t)pms[kk] * DD + d];
      r1 += e1 * h; r2 += e2 * h;
      if (d == 0) { p1s[k] = sr1; p2s[k] = sr2; sr1 += e1; sr2 += e2; }
    }
    if (b == NC - 1) {
      PRE1[(size_t)NN * DD + d] = r1;
      PRE2[(size_t)NN * DD + d] = r2;
      if (d == 0) { p1s[NN] = sr1; p2s[NN] = sr2; }
    }
  }
  gridbar(bcnt, bgen);  // PRE, p1s, p2s complete

  // ================= phase E: finalize rows b*32..b*32+31 =================
  {
    float* ts = smem;
#pragma unroll
    for (int q = 0; q < NN / 1024; ++q) {
      int idx = (q * 256 + tid) * 4;
      *reinterpret_cast<f4*>(&ts[idx]) = *reinterpret_cast<const f4*>(&tsort[idx]);
    }
    __syncthreads();
    int kk[8];
#pragma unroll
    for (int it = 0; it < 8; ++it) {
      int i = b * 32 + it * 4 + wid;
      float key = -s[i];
      int lo = 0, hi = NN;
      while (lo < hi) {
        int mid = (lo + hi) >> 1;
        if (ts[mid] <= key) lo = mid + 1; else hi = mid;
      }
      kk[it] = lo;
    }
    int d = lane * 4;
    f4 T1 = *reinterpret_cast<const f4*>(&PRE1[(size_t)NN * DD + d]);
    float tot1 = p1s[NN];
#pragma unroll
    for (int it = 0; it < 8; ++it) {
      int i = b * 32 + it * 4 + wid;
      int k = kk[it];
      float cc1 = c1[i], cc2 = c2[i];
      float Z = cc1 * (tot1 - p1s[k]) + cc2 * p2s[k];
      float rZ = 1.0f / Z;
      if (lane == 0) { f1[i] = rZ * cc1; f2[i] = rZ * cc2; }
      f4 P1 = *reinterpret_cast<const f4*>(&PRE1[(size_t)k * DD + d]);
      f4 P2 = *reinterpret_cast<const f4*>(&PRE2[(size_t)k * DD + d]);
      f4 o;
      o.x = rZ * (cc1 * (T1.x - P1.x) + cc2 * P2.x);
      o.y = rZ * (cc1 * (T1.y - P1.y) + cc2 * P2.y);
      o.z = rZ * (cc1 * (T1.z - P1.z) + cc2 * P2.z);
      o.w = rZ * (cc1 * (T1.w - P1.w) + cc2 * P2.w);
      *reinterpret_cast<f4*>(&out[(size_t)i * DD + d]) = o;
    }
  }
  gridbar(bcnt, bgen);  // f1, f2 complete; scratch in A-region now dead

  // ================= phase F: stream A rows b*32..b*32+31 =================
  {
    if (tid < 32) {
      int i = b * 32 + tid;
      srow[tid] = s[i];
      f1r[tid] = f1[i];
      f2r[tid] = f2[i];
    }
    __syncthreads();
#pragma unroll
    for (int jq = 0; jq < 8; ++jq) {
      int j0 = jq * 1024 + tid * 4;
      f4 t4  = *reinterpret_cast<const f4*>(&t[j0]);
      f4 e14 = *reinterpret_cast<const f4*>(&E1[j0]);
      f4 e24 = *reinterpret_cast<const f4*>(&E2[j0]);
#pragma unroll 4
      for (int rr = 0; rr < 32; ++rr) {
        int i = b * 32 + rr;
        float ss = srow[rr], ff1 = f1r[rr], ff2 = f2r[rr];
        f4v o;
        float e;
        e = ss + t4.x; o.x = (e > 0.f) ? ff1 * e14.x : ff2 * e24.x;
        e = ss + t4.y; o.y = (e > 0.f) ? ff1 * e14.y : ff2 * e24.y;
        e = ss + t4.z; o.z = (e > 0.f) ? ff1 * e14.z : ff2 * e24.z;
        e = ss + t4.w; o.w = (e > 0.f) ? ff1 * e14.w : ff2 * e24.w;
        __builtin_nontemporal_store(o, reinterpret_cast<f4v*>(&Ab[(size_t)i * NN + j0]));
      }
    }
  }
}

extern "C" void kernel_launch(void* const* d_in, const int* in_sizes, int n_in,
                              void* d_out, int out_size, void* d_ws, size_t ws_size,
                              hipStream_t stream) {
  const float* X  = (const float*)d_in[0];
  const float* W  = (const float*)d_in[1];
  const float* av = (const float*)d_in[2];
  float* outp = (float*)d_out;                  // [NN*DD]
  float* Ap   = outp + (size_t)NN * DD;         // [NN*NN]
  float* wsp  = (float*)d_ws;

  // zero the grid-barrier words (cnt, gen) -- stream-ordered, graph-capturable
  hipMemsetAsync((void*)(Ap + 8600000), 0, 8, stream);

  void* cargs[] = {(void*)&X, (void*)&W, (void*)&av,
                   (void*)&outp, (void*)&Ap, (void*)&wsp};
  hipLaunchCooperativeKernel((void*)k_fused, dim3(NB), dim3(256), cargs, 0, stream);
}